// Round 7
// baseline (625.686 us; speedup 1.0000x reference)
//
#include <hip/hip_runtime.h>
#include <hip/hip_bf16.h>

#define H 128
#define NGRAPH 64
#define NLAYERS 2
#define TMM 64          // rows per MLP block
#define TP 136          // t-tile LDS row stride in bf16 (pad 8)
#define BSH 8           // bucket shift: 256 nodes per bucket
#define MAXB 512        // max buckets (n <= 131072)

typedef short short8 __attribute__((ext_vector_type(8)));
typedef float floatx4 __attribute__((ext_vector_type(4)));
typedef float floatx2 __attribute__((ext_vector_type(2)));

static __device__ __forceinline__ unsigned short f2bf(float v) {
    __hip_bfloat16 b = __float2bfloat16(v);
    return *(unsigned short*)&b;
}
static __device__ __forceinline__ float bf2f(unsigned short u) {
    return __uint_as_float(((unsigned int)u) << 16);
}
// pack 4 f32 -> 4 fp8(e4m3) bytes
static __device__ __forceinline__ int pack4_fp8(float a, float b, float c, float d) {
    int p = __builtin_amdgcn_cvt_pk_fp8_f32(a, b, 0, false);
    p = __builtin_amdgcn_cvt_pk_fp8_f32(c, d, p, true);
    return p;
}

// ------- encoder: h = bf16(x*w+b), plus fp8 shadow h8 for gathers -------
__global__ void enc_kernel(const float* __restrict__ x, const float* __restrict__ w,
                           const float* __restrict__ b, unsigned short* __restrict__ h,
                           unsigned char* __restrict__ h8, int n) {
    int t = blockIdx.x * blockDim.x + threadIdx.x;
    int i = t >> 5;            // node
    int c = (t & 31) << 2;     // feature*4
    if (i >= n) return;
    float xv = x[i];
    float4 wv = *(const float4*)(w + c);
    float4 bv = *(const float4*)(b + c);
    float4 o;
    o.x = xv * wv.x + bv.x;
    o.y = xv * wv.y + bv.y;
    o.z = xv * wv.z + bv.z;
    o.w = xv * wv.w + bv.w;
    ushort4 ob;
    ob.x = f2bf(o.x); ob.y = f2bf(o.y); ob.z = f2bf(o.z); ob.w = f2bf(o.w);
    *(ushort4*)(h + (size_t)i * H + c) = ob;
    *(int*)(h8 + (size_t)i * H + c) = pack4_fp8(o.x, o.y, o.z, o.w);
}

// ------- cast bf16 h -> fp8 shadow (after layer-0 MLP) -------
__global__ void cast_kernel(const unsigned short* __restrict__ h,
                            unsigned char* __restrict__ h8, int n) {
    int t = blockIdx.x * blockDim.x + threadIdx.x;
    int i = t >> 5;
    int c = (t & 31) << 2;
    if (i >= n) return;
    ushort4 v = *(const ushort4*)(h + (size_t)i * H + c);
    *(int*)(h8 + (size_t)i * H + c) =
        pack4_fp8(bf2f(v.x), bf2f(v.y), bf2f(v.z), bf2f(v.w));
}

// ------- prep: cast+transpose mlp weights to bf16 [l][n][k] -------
__global__ void prep_kernel(const float* __restrict__ w1, const float* __restrict__ w2,
                            unsigned short* __restrict__ w1t, unsigned short* __restrict__ w2t) {
    int idx = blockIdx.x * blockDim.x + threadIdx.x;   // 2*128*128
    int l = idx >> 14;
    int r = idx & 16383;
    int nn = r >> 7;
    int kk = r & 127;
    w1t[(size_t)l * 16384 + nn * 128 + kk] = f2bf(w1[(size_t)l * 16384 + kk * 128 + nn]);
    w2t[(size_t)l * 16384 + nn * 128 + kk] = f2bf(w2[(size_t)l * 16384 + kk * 128 + nn]);
}

// ---------------- counting-sort by dst: histogram ----------------
__global__ void hist_kernel(const int* __restrict__ ei, int* __restrict__ deg, int ne) {
    int e = blockIdx.x * blockDim.x + threadIdx.x;
    if (e >= ne) return;
    atomicAdd(&deg[ei[ne + e]], 1);
}

// -------- hierarchical exclusive scan, level 1: 1024 elems per block --------
__global__ __launch_bounds__(256) void scan1_kernel(const int* __restrict__ deg,
                                                    int* __restrict__ start,
                                                    int* __restrict__ bsum, int n) {
    __shared__ int wsum[4];
    const int t = threadIdx.x;
    const int lane = t & 63;
    const int wid = t >> 6;
    const int base = blockIdx.x * 1024 + t * 4;
    int4 v = make_int4(0, 0, 0, 0);
    if (base + 3 < n) v = *(const int4*)(deg + base);
    else {
        if (base + 0 < n) v.x = deg[base + 0];
        if (base + 1 < n) v.y = deg[base + 1];
        if (base + 2 < n) v.z = deg[base + 2];
    }
    int s = v.x + v.y + v.z + v.w;
    int incl = s;
    #pragma unroll
    for (int off = 1; off < 64; off <<= 1) {
        int u = __shfl_up(incl, off, 64);
        if (lane >= off) incl += u;
    }
    if (lane == 63) wsum[wid] = incl;
    __syncthreads();
    int woff = 0;
    #pragma unroll
    for (int k = 0; k < 4; ++k) if (k < wid) woff += wsum[k];
    int excl = woff + incl - s;
    int4 o;
    o.x = excl;
    o.y = o.x + v.x;
    o.z = o.y + v.y;
    o.w = o.z + v.z;
    if (base + 3 < n) *(int4*)(start + base) = o;
    else {
        if (base + 0 < n) start[base + 0] = o.x;
        if (base + 1 < n) start[base + 1] = o.y;
        if (base + 2 < n) start[base + 2] = o.z;
    }
    if (t == 255) bsum[blockIdx.x] = woff + incl;
}

// -------- scan level 2: scan block sums (nb <= 256), write total to start[n] --
__global__ __launch_bounds__(256) void scan2_kernel(const int* __restrict__ bsum,
                                                    int* __restrict__ bscan,
                                                    int* __restrict__ start, int nb, int n) {
    __shared__ int wsum[4];
    const int t = threadIdx.x;
    const int lane = t & 63;
    const int wid = t >> 6;
    int v = (t < nb) ? bsum[t] : 0;
    int incl = v;
    #pragma unroll
    for (int off = 1; off < 64; off <<= 1) {
        int u = __shfl_up(incl, off, 64);
        if (lane >= off) incl += u;
    }
    if (lane == 63) wsum[wid] = incl;
    __syncthreads();
    int woff = 0;
    #pragma unroll
    for (int k = 0; k < 4; ++k) if (k < wid) woff += wsum[k];
    if (t < nb) bscan[t] = woff + incl - v;
    if (t == 255) start[n] = woff + incl;
}

// -------- scan level 3: add block offsets --------
__global__ void scan3_kernel(int* __restrict__ start, const int* __restrict__ bscan, int n) {
    int i = blockIdx.x * blockDim.x + threadIdx.x;
    if (i < n) start[i] += bscan[i >> 10];
}

// ---- sort phase A: bin edges into 256-node buckets, block-coalesced runs ----
// entry: x = src, y = (attr_bf16 << 16) | local_dst(8b)
__global__ __launch_bounds__(256) void binA_kernel(
    const int* __restrict__ ei, const float* __restrict__ ea,
    const int* __restrict__ start, int* __restrict__ bcursor,
    int2* __restrict__ sedge2, int ne, int n, int nbuck) {
    __shared__ int hist[MAXB];
    __shared__ int gpos[MAXB];
    const int t = threadIdx.x;
    const int e0 = blockIdx.x * 4096;
    for (int k = t; k < MAXB; k += 256) hist[k] = 0;
    __syncthreads();
    int dsts[16];
    #pragma unroll
    for (int k = 0; k < 16; ++k) {
        int e = e0 + k * 256 + t;
        int d = (e < ne) ? ei[ne + e] : -1;
        dsts[k] = d;
        if (d >= 0) atomicAdd(&hist[d >> BSH], 1);
    }
    __syncthreads();
    for (int b = t; b < nbuck; b += 256) {
        int c = hist[b];
        gpos[b] = (c > 0) ? (start[b << BSH] + atomicAdd(&bcursor[b], c)) : 0;
    }
    __syncthreads();
    for (int k = t; k < MAXB; k += 256) hist[k] = 0;   // reuse as local cursor
    __syncthreads();
    #pragma unroll
    for (int k = 0; k < 16; ++k) {
        int d = dsts[k];
        if (d >= 0) {
            int e = e0 + k * 256 + t;
            int b = d >> BSH;
            int idx = atomicAdd(&hist[b], 1);
            int2 p;
            p.x = ei[e];
            p.y = ((int)f2bf(ea[e]) << 16) | (d & ((1 << BSH) - 1));
            sedge2[gpos[b] + idx] = p;
        }
    }
}

// ---- sort phase B: exact scatter within bucket (one block per bucket) ----
__global__ __launch_bounds__(256) void binB_kernel(
    const int2* __restrict__ sedge2, const int* __restrict__ start,
    int2* __restrict__ sedge, int n) {
    __shared__ int lcur[1 << BSH];
    const int node0 = blockIdx.x << BSH;
    const int t = threadIdx.x;
    lcur[t] = 0;
    __syncthreads();
    int s0 = start[node0];
    int s1 = start[min(node0 + (1 << BSH), n)];
    for (int i = s0 + t; i < s1; i += 256) {
        int2 p = sedge2[i];
        int ld = p.y & ((1 << BSH) - 1);
        int idx = atomicAdd(&lcur[ld], 1);
        sedge[start[node0 + ld] + idx] = p;
    }
}

// ---- segment-reduce gather: z[i] = (1+eps)*h[i] + sum_j relu(h8[src_j]+e_j) ----
// one wave per node; fp8 h rows (128 B gather), f32 accumulate, bf16 z out
__global__ __launch_bounds__(256) void aggregate_kernel(
    const unsigned short* __restrict__ h, const unsigned char* __restrict__ h8,
    const int* __restrict__ start, const int2* __restrict__ sedge,
    const float* __restrict__ ew, const float* __restrict__ eb,
    const float* __restrict__ epsp, int layer,
    unsigned short* __restrict__ z, int n) {
    int node = (blockIdx.x * blockDim.x + threadIdx.x) >> 6;
    int lane = threadIdx.x & 63;
    if (node >= n) return;
    int c = lane << 1;
    float2 wv = *(const float2*)(ew + c);
    float2 bv = *(const float2*)(eb + c);
    float2 acc = make_float2(0.f, 0.f);
    int s0 = start[node], s1 = start[node + 1];
    int j = s0;
    for (; j + 16 <= s1; j += 16) {
        int2 e[16];
        unsigned short v8[16];
        #pragma unroll
        for (int k = 0; k < 16; ++k) e[k] = sedge[j + k];
        #pragma unroll
        for (int k = 0; k < 16; ++k)
            v8[k] = *(const unsigned short*)(h8 + (size_t)e[k].x * H + c);
        #pragma unroll
        for (int k = 0; k < 16; ++k) {
            float a = __uint_as_float((unsigned)e[k].y & 0xffff0000u);
            floatx2 hv = __builtin_amdgcn_cvt_pk_f32_fp8((int)v8[k], false);
            acc.x += fmaxf(fmaf(a, wv.x, bv.x) + hv.x, 0.f);
            acc.y += fmaxf(fmaf(a, wv.y, bv.y) + hv.y, 0.f);
        }
    }
    for (; j < s1; ++j) {
        int2 e = sedge[j];
        float a = __uint_as_float((unsigned)e.y & 0xffff0000u);
        unsigned short u8 = *(const unsigned short*)(h8 + (size_t)e.x * H + c);
        floatx2 hv = __builtin_amdgcn_cvt_pk_f32_fp8((int)u8, false);
        acc.x += fmaxf(fmaf(a, wv.x, bv.x) + hv.x, 0.f);
        acc.y += fmaxf(fmaf(a, wv.y, bv.y) + hv.y, 0.f);
    }
    float ev = 1.0f + epsp[layer];
    ushort2 hv = *(const ushort2*)(h + (size_t)node * H + c);
    ushort2 p;
    p.x = f2bf(fmaf(ev, bf2f(hv.x), acc.x));
    p.y = f2bf(fmaf(ev, bf2f(hv.y), acc.y));
    *(ushort2*)(z + (size_t)node * H + c) = p;
}

// ---- MFMA node MLP: h = bf16(relu(BN(relu(z@w1+b1)@w2+b2))), bf16 in/out ----
__global__ __launch_bounds__(256) void mfma_mlp_kernel(
    unsigned short* __restrict__ h, const unsigned short* __restrict__ z,
    const unsigned short* __restrict__ w1t, const float* __restrict__ b1,
    const unsigned short* __restrict__ w2t, const float* __restrict__ b2,
    const float* __restrict__ gamma, const float* __restrict__ beta,
    const float* __restrict__ mean, const float* __restrict__ var, int n) {
    __shared__ unsigned short ts[TMM * TP];
    const int tid = threadIdx.x;
    const int wid = tid >> 6;
    const int lane = tid & 63;
    const int m = lane & 15;     // A row within 16 / B col
    const int q = lane >> 4;     // quad
    const int row0 = blockIdx.x * TMM + wid * 16;

    // ---------- GEMM1: t = relu(z @ w1 + b1) ----------
    floatx4 acc[8];
    #pragma unroll
    for (int ct = 0; ct < 8; ++ct) acc[ct] = (floatx4)(0.f);

    const unsigned short* zrow = z + (size_t)(row0 + m) * H + q * 8;
    #pragma unroll
    for (int kb = 0; kb < H; kb += 32) {
        short8 a = *(const short8*)(zrow + kb);
        #pragma unroll
        for (int ct = 0; ct < 8; ++ct) {
            short8 b = *(const short8*)(w1t + (size_t)(ct * 16 + m) * H + kb + q * 8);
            acc[ct] = __builtin_amdgcn_mfma_f32_16x16x32_bf16(a, b, acc[ct], 0, 0, 0);
        }
    }
    unsigned short* tw = ts + wid * 16 * TP;
    #pragma unroll
    for (int ct = 0; ct < 8; ++ct) {
        float bb = b1[ct * 16 + m];
        #pragma unroll
        for (int r = 0; r < 4; ++r) {
            float v = fmaxf(acc[ct][r] + bb, 0.f);
            tw[(q * 4 + r) * TP + ct * 16 + m] = f2bf(v);
        }
    }

    // ---------- GEMM2: z2 = t @ w2 + b2, then BN + relu ----------
    floatx4 acc2[8];
    #pragma unroll
    for (int ct = 0; ct < 8; ++ct) acc2[ct] = (floatx4)(0.f);

    const unsigned short* trow = tw + m * TP + q * 8;
    #pragma unroll
    for (int kb = 0; kb < H; kb += 32) {
        short8 a = *(const short8*)(trow + kb);
        #pragma unroll
        for (int ct = 0; ct < 8; ++ct) {
            short8 b = *(const short8*)(w2t + (size_t)(ct * 16 + m) * H + kb + q * 8);
            acc2[ct] = __builtin_amdgcn_mfma_f32_16x16x32_bf16(a, b, acc2[ct], 0, 0, 0);
        }
    }
    #pragma unroll
    for (int ct = 0; ct < 8; ++ct) {
        int col = ct * 16 + m;
        float bb = b2[col];
        float sc = gamma[col] * rsqrtf(var[col] + 1e-5f);
        float mn = mean[col];
        float bt = beta[col];
        #pragma unroll
        for (int r = 0; r < 4; ++r) {
            int grow = row0 + q * 4 + r;
            if (grow < n) {
                float v = fmaxf((acc2[ct][r] + bb - mn) * sc + bt, 0.f);
                h[(size_t)grow * H + col] = f2bf(v);
            }
        }
    }
}

// ---- graph boundaries from sorted batch: gstart[g] = first node of graph g ----
__global__ void gbound_kernel(const int* __restrict__ batch, int* __restrict__ gstart, int n) {
    int i = blockIdx.x * blockDim.x + threadIdx.x;
    if (i >= n) return;
    int b = batch[i];
    if (i == 0) {
        for (int g = 0; g <= b; ++g) gstart[g] = 0;
    } else {
        int p = batch[i - 1];
        for (int g = p + 1; g <= b; ++g) gstart[g] = i;
    }
    if (i == n - 1) {
        for (int g = b + 1; g <= NGRAPH; ++g) gstart[g] = n;
    }
}

// ---- global mean pool: segmented gather of bf16 h, LDS reduce, few atomics ----
__global__ __launch_bounds__(256) void pool_kernel(const unsigned short* __restrict__ h,
                                                   const int* __restrict__ gstart,
                                                   float* __restrict__ sums) {
    __shared__ float4 buf[8][32];
    const int g = blockIdx.x;       // graph
    const int split = blockIdx.y;   // 0..7
    const int t = threadIdx.x;
    const int c32 = t & 31;
    const int c = c32 << 2;
    const int r = t >> 5;           // 0..7
    int s0 = gstart[g], s1 = gstart[g + 1];
    int len = s1 - s0;
    int chunk = (len + 7) >> 3;
    int a = s0 + split * chunk;
    int b = min(a + chunk, s1);
    float4 acc = make_float4(0.f, 0.f, 0.f, 0.f);
    for (int i = a + r; i < b; i += 8) {
        ushort4 v = *(const ushort4*)(h + (size_t)i * H + c);
        acc.x += bf2f(v.x); acc.y += bf2f(v.y); acc.z += bf2f(v.z); acc.w += bf2f(v.w);
    }
    buf[r][c32] = acc;
    __syncthreads();
    if (r == 0) {
        float4 s = buf[0][c32];
        #pragma unroll
        for (int k = 1; k < 8; ++k) {
            float4 v = buf[k][c32];
            s.x += v.x; s.y += v.y; s.z += v.z; s.w += v.w;
        }
        float* sp = sums + (size_t)g * H + c;
        atomicAdd(sp + 0, s.x);
        atomicAdd(sp + 1, s.y);
        atomicAdd(sp + 2, s.z);
        atomicAdd(sp + 3, s.w);
    }
}

// ---------------- classifier: sigmoid(relu(g@w1+b1)@w2+b2) ----------------
__global__ void cls_kernel(const float* __restrict__ sums, const int* __restrict__ gstart,
                           const float* __restrict__ w1, const float* __restrict__ b1,
                           const float* __restrict__ w2, const float* __restrict__ b2,
                           float* __restrict__ out) {
    int g = blockIdx.x;     // 64 graphs
    int m = threadIdx.x;    // 64 mids
    float cnt = (float)(gstart[g + 1] - gstart[g]);
    float inv = 1.0f / fmaxf(cnt, 1.0f);
    float acc = 0.f;
    for (int k = 0; k < H; ++k) {
        float gk = sums[(size_t)g * H + k] * inv;
        acc += gk * w1[(size_t)k * 64 + m];
    }
    float tm = fmaxf(acc + b1[m], 0.f);
    float p = tm * w2[m];
    #pragma unroll
    for (int off = 32; off > 0; off >>= 1) p += __shfl_down(p, off, 64);
    if (m == 0) out[g] = 1.f / (1.f + expf(-(p + b2[0])));
}

extern "C" void kernel_launch(void* const* d_in, const int* in_sizes, int n_in,
                              void* d_out, int out_size, void* d_ws, size_t ws_size,
                              hipStream_t stream) {
    const float* x      = (const float*)d_in[0];
    const int*   ei     = (const int*)d_in[1];
    const float* ea     = (const float*)d_in[2];
    const int*   batch  = (const int*)d_in[3];
    const float* enc_w  = (const float*)d_in[4];
    const float* enc_b  = (const float*)d_in[5];
    const float* edge_w = (const float*)d_in[6];
    const float* edge_b = (const float*)d_in[7];
    const float* eps    = (const float*)d_in[8];
    const float* mlp_w1 = (const float*)d_in[9];
    const float* mlp_b1 = (const float*)d_in[10];
    const float* mlp_w2 = (const float*)d_in[11];
    const float* mlp_b2 = (const float*)d_in[12];
    const float* bn_g   = (const float*)d_in[13];
    const float* bn_b   = (const float*)d_in[14];
    const float* bn_m   = (const float*)d_in[15];
    const float* bn_v   = (const float*)d_in[16];
    const float* cls_w1 = (const float*)d_in[17];
    const float* cls_b1 = (const float*)d_in[18];
    const float* cls_w2 = (const float*)d_in[19];
    const float* cls_b2 = (const float*)d_in[20];
    float* out = (float*)d_out;

    const int n = in_sizes[0];        // 100000
    const int ne = in_sizes[2];       // 1600000
    const int nb = (n + 1023) / 1024; // scan blocks
    const int nbuck = (n + (1 << BSH) - 1) >> BSH;  // 256-node buckets

    // workspace layout (regions kept 16B-aligned)
    unsigned short* hb  = (unsigned short*)d_ws;                    // N*H bf16
    unsigned short* zb  = hb + (size_t)n * H;                       // N*H bf16
    unsigned char* h8   = (unsigned char*)(zb + (size_t)n * H);     // N*H fp8
    float* sums         = (float*)(h8 + (size_t)n * H);             // G*H
    int*   gstart       = (int*)(sums + (size_t)NGRAPH * H);        // G+4
    int*   deg          = gstart + NGRAPH + 4;                      // N
    int*   start        = deg + n;                                  // N+4
    int*   bcursor      = start + n + 4;                            // MAXB
    int*   bsum         = bcursor + MAXB;                           // 256
    int*   bscan        = bsum + 256;                               // 256
    unsigned short* w1t = (unsigned short*)(bscan + 256);           // 2*128*128
    unsigned short* w2t = w1t + 2 * 16384;                          // 2*128*128
    int2*  sedge2       = (int2*)(w2t + 2 * 16384);                 // E (binned)
    int2*  sedge        = sedge2 + ne;                              // E (sorted)

    hipMemsetAsync(sums, 0, (size_t)NGRAPH * H * sizeof(float), stream);
    hipMemsetAsync(deg, 0, (size_t)n * sizeof(int), stream);
    hipMemsetAsync(bcursor, 0, (size_t)MAXB * sizeof(int), stream);

    // weight prep (bf16 transpose) — once per call
    prep_kernel<<<128, 256, 0, stream>>>(mlp_w1, mlp_w2, w1t, w2t);

    // ---- counting sort of edges by dst (once; reused both layers) ----
    hist_kernel<<<(ne + 255) / 256, 256, 0, stream>>>(ei, deg, ne);
    scan1_kernel<<<nb, 256, 0, stream>>>(deg, start, bsum, n);
    scan2_kernel<<<1, 256, 0, stream>>>(bsum, bscan, start, nb, n);
    scan3_kernel<<<(n + 255) / 256, 256, 0, stream>>>(start, bscan, n);
    binA_kernel<<<(ne + 4095) / 4096, 256, 0, stream>>>(ei, ea, start, bcursor, sedge2, ne, n, nbuck);
    binB_kernel<<<nbuck, 256, 0, stream>>>(sedge2, start, sedge, n);

    // graph boundaries for pooling
    gbound_kernel<<<(n + 255) / 256, 256, 0, stream>>>(batch, gstart, n);

    // encoder (writes bf16 h and fp8 shadow)
    {
        int threads = n * 32;
        enc_kernel<<<(threads + 255) / 256, 256, 0, stream>>>(x, enc_w, enc_b, hb, h8, n);
    }

    for (int l = 0; l < NLAYERS; ++l) {
        {
            int threads = n * 64;
            aggregate_kernel<<<(threads + 255) / 256, 256, 0, stream>>>(
                hb, h8, start, sedge, edge_w, edge_b, eps, l, zb, n);
        }
        mfma_mlp_kernel<<<(n + TMM - 1) / TMM, 256, 0, stream>>>(
            hb, zb,
            w1t + (size_t)l * 16384, mlp_b1 + (size_t)l * H,
            w2t + (size_t)l * 16384, mlp_b2 + (size_t)l * H,
            bn_g + (size_t)l * H, bn_b + (size_t)l * H,
            bn_m + (size_t)l * H, bn_v + (size_t)l * H, n);
        if (l == 0) {
            int threads = n * 32;
            cast_kernel<<<(threads + 255) / 256, 256, 0, stream>>>(hb, h8, n);
        }
    }

    pool_kernel<<<dim3(NGRAPH, 8), 256, 0, stream>>>(hb, gstart, sums);
    cls_kernel<<<NGRAPH, 64, 0, stream>>>(sums, gstart, cls_w1, cls_b1, cls_w2, cls_b2, out);
}

// Round 8
// 561.080 us; speedup vs baseline: 1.1151x; 1.1151x over previous
//
#include <hip/hip_runtime.h>
#include <hip/hip_bf16.h>

#define H 128
#define NGRAPH 64
#define NLAYERS 2
#define TMM 64          // rows per MLP block
#define TP 136          // t-tile LDS row stride in bf16 (pad 8)
#define BSH 8           // bucket shift: 256 nodes per bucket
#define MAXB 512        // max buckets (n <= 131072)

typedef short short8 __attribute__((ext_vector_type(8)));
typedef float floatx4 __attribute__((ext_vector_type(4)));
typedef float floatx2 __attribute__((ext_vector_type(2)));

static __device__ __forceinline__ unsigned short f2bf(float v) {
    __hip_bfloat16 b = __float2bfloat16(v);
    return *(unsigned short*)&b;
}
static __device__ __forceinline__ float bf2f(unsigned short u) {
    return __uint_as_float(((unsigned int)u) << 16);
}
// pack 4 f32 -> 4 fp8(e4m3) bytes
static __device__ __forceinline__ int pack4_fp8(float a, float b, float c, float d) {
    int p = __builtin_amdgcn_cvt_pk_fp8_f32(a, b, 0, false);
    p = __builtin_amdgcn_cvt_pk_fp8_f32(c, d, p, true);
    return p;
}

// ------- encoder: h = bf16(x*w+b), plus fp8 shadow h8 for gathers -------
__global__ void enc_kernel(const float* __restrict__ x, const float* __restrict__ w,
                           const float* __restrict__ b, unsigned short* __restrict__ h,
                           unsigned char* __restrict__ h8, int n) {
    int t = blockIdx.x * blockDim.x + threadIdx.x;
    int i = t >> 5;            // node
    int c = (t & 31) << 2;     // feature*4
    if (i >= n) return;
    float xv = x[i];
    float4 wv = *(const float4*)(w + c);
    float4 bv = *(const float4*)(b + c);
    float4 o;
    o.x = xv * wv.x + bv.x;
    o.y = xv * wv.y + bv.y;
    o.z = xv * wv.z + bv.z;
    o.w = xv * wv.w + bv.w;
    ushort4 ob;
    ob.x = f2bf(o.x); ob.y = f2bf(o.y); ob.z = f2bf(o.z); ob.w = f2bf(o.w);
    *(ushort4*)(h + (size_t)i * H + c) = ob;
    *(int*)(h8 + (size_t)i * H + c) = pack4_fp8(o.x, o.y, o.z, o.w);
}

// ------- cast bf16 h -> fp8 shadow (after layer-0 MLP) -------
__global__ void cast_kernel(const unsigned short* __restrict__ h,
                            unsigned char* __restrict__ h8, int n) {
    int t = blockIdx.x * blockDim.x + threadIdx.x;
    int i = t >> 5;
    int c = (t & 31) << 2;
    if (i >= n) return;
    ushort4 v = *(const ushort4*)(h + (size_t)i * H + c);
    *(int*)(h8 + (size_t)i * H + c) =
        pack4_fp8(bf2f(v.x), bf2f(v.y), bf2f(v.z), bf2f(v.w));
}

// ------- prep: cast+transpose mlp weights to bf16 [l][n][k] -------
__global__ void prep_kernel(const float* __restrict__ w1, const float* __restrict__ w2,
                            unsigned short* __restrict__ w1t, unsigned short* __restrict__ w2t) {
    int idx = blockIdx.x * blockDim.x + threadIdx.x;   // 2*128*128
    int l = idx >> 14;
    int r = idx & 16383;
    int nn = r >> 7;
    int kk = r & 127;
    w1t[(size_t)l * 16384 + nn * 128 + kk] = f2bf(w1[(size_t)l * 16384 + kk * 128 + nn]);
    w2t[(size_t)l * 16384 + nn * 128 + kk] = f2bf(w2[(size_t)l * 16384 + kk * 128 + nn]);
}

// ---------------- counting-sort by dst: histogram ----------------
__global__ void hist_kernel(const int* __restrict__ ei, int* __restrict__ deg, int ne) {
    int e = blockIdx.x * blockDim.x + threadIdx.x;
    if (e >= ne) return;
    atomicAdd(&deg[ei[ne + e]], 1);
}

// -------- hierarchical exclusive scan, level 1: 1024 elems per block --------
__global__ __launch_bounds__(256) void scan1_kernel(const int* __restrict__ deg,
                                                    int* __restrict__ start,
                                                    int* __restrict__ bsum, int n) {
    __shared__ int wsum[4];
    const int t = threadIdx.x;
    const int lane = t & 63;
    const int wid = t >> 6;
    const int base = blockIdx.x * 1024 + t * 4;
    int4 v = make_int4(0, 0, 0, 0);
    if (base + 3 < n) v = *(const int4*)(deg + base);
    else {
        if (base + 0 < n) v.x = deg[base + 0];
        if (base + 1 < n) v.y = deg[base + 1];
        if (base + 2 < n) v.z = deg[base + 2];
    }
    int s = v.x + v.y + v.z + v.w;
    int incl = s;
    #pragma unroll
    for (int off = 1; off < 64; off <<= 1) {
        int u = __shfl_up(incl, off, 64);
        if (lane >= off) incl += u;
    }
    if (lane == 63) wsum[wid] = incl;
    __syncthreads();
    int woff = 0;
    #pragma unroll
    for (int k = 0; k < 4; ++k) if (k < wid) woff += wsum[k];
    int excl = woff + incl - s;
    int4 o;
    o.x = excl;
    o.y = o.x + v.x;
    o.z = o.y + v.y;
    o.w = o.z + v.z;
    if (base + 3 < n) *(int4*)(start + base) = o;
    else {
        if (base + 0 < n) start[base + 0] = o.x;
        if (base + 1 < n) start[base + 1] = o.y;
        if (base + 2 < n) start[base + 2] = o.z;
    }
    if (t == 255) bsum[blockIdx.x] = woff + incl;
}

// -------- scan level 2: scan block sums (nb <= 256), write total to start[n] --
__global__ __launch_bounds__(256) void scan2_kernel(const int* __restrict__ bsum,
                                                    int* __restrict__ bscan,
                                                    int* __restrict__ start, int nb, int n) {
    __shared__ int wsum[4];
    const int t = threadIdx.x;
    const int lane = t & 63;
    const int wid = t >> 6;
    int v = (t < nb) ? bsum[t] : 0;
    int incl = v;
    #pragma unroll
    for (int off = 1; off < 64; off <<= 1) {
        int u = __shfl_up(incl, off, 64);
        if (lane >= off) incl += u;
    }
    if (lane == 63) wsum[wid] = incl;
    __syncthreads();
    int woff = 0;
    #pragma unroll
    for (int k = 0; k < 4; ++k) if (k < wid) woff += wsum[k];
    if (t < nb) bscan[t] = woff + incl - v;
    if (t == 255) start[n] = woff + incl;
}

// -------- scan level 3: add block offsets --------
__global__ void scan3_kernel(int* __restrict__ start, const int* __restrict__ bscan, int n) {
    int i = blockIdx.x * blockDim.x + threadIdx.x;
    if (i < n) start[i] += bscan[i >> 10];
}

// ---- sort phase A: bin edges into 256-node buckets, block-coalesced runs ----
// entry: x = src, y = (attr_bf16 << 16) | local_dst(8b)
__global__ __launch_bounds__(256) void binA_kernel(
    const int* __restrict__ ei, const float* __restrict__ ea,
    const int* __restrict__ start, int* __restrict__ bcursor,
    int2* __restrict__ sedge2, int ne, int n, int nbuck) {
    __shared__ int hist[MAXB];
    __shared__ int gpos[MAXB];
    const int t = threadIdx.x;
    const int e0 = blockIdx.x * 4096;
    for (int k = t; k < MAXB; k += 256) hist[k] = 0;
    __syncthreads();
    int dsts[16];
    #pragma unroll
    for (int k = 0; k < 16; ++k) {
        int e = e0 + k * 256 + t;
        int d = (e < ne) ? ei[ne + e] : -1;
        dsts[k] = d;
        if (d >= 0) atomicAdd(&hist[d >> BSH], 1);
    }
    __syncthreads();
    for (int b = t; b < nbuck; b += 256) {
        int c = hist[b];
        gpos[b] = (c > 0) ? (start[b << BSH] + atomicAdd(&bcursor[b], c)) : 0;
    }
    __syncthreads();
    for (int k = t; k < MAXB; k += 256) hist[k] = 0;   // reuse as local cursor
    __syncthreads();
    #pragma unroll
    for (int k = 0; k < 16; ++k) {
        int d = dsts[k];
        if (d >= 0) {
            int e = e0 + k * 256 + t;
            int b = d >> BSH;
            int idx = atomicAdd(&hist[b], 1);
            int2 p;
            p.x = ei[e];
            p.y = ((int)f2bf(ea[e]) << 16) | (d & ((1 << BSH) - 1));
            sedge2[gpos[b] + idx] = p;
        }
    }
}

// ---- sort phase B: exact scatter within bucket (one block per bucket) ----
__global__ __launch_bounds__(256) void binB_kernel(
    const int2* __restrict__ sedge2, const int* __restrict__ start,
    int2* __restrict__ sedge, int n) {
    __shared__ int lcur[1 << BSH];
    const int node0 = blockIdx.x << BSH;
    const int t = threadIdx.x;
    lcur[t] = 0;
    __syncthreads();
    int s0 = start[node0];
    int s1 = start[min(node0 + (1 << BSH), n)];
    for (int i = s0 + t; i < s1; i += 256) {
        int2 p = sedge2[i];
        int ld = p.y & ((1 << BSH) - 1);
        int idx = atomicAdd(&lcur[ld], 1);
        sedge[start[node0 + ld] + idx] = p;
    }
}

// ---- segment-reduce gather: z[i] = (1+eps)*h[i] + sum_j relu(h8[src_j]+e_j) ----
// one wave per node; fp8 h rows (128 B gather), predicated 8-wide chunks
// (no scalar tail: clamped indices + 0/1 mask keep every edge on the batched path)
__global__ __launch_bounds__(256) void aggregate_kernel(
    const unsigned short* __restrict__ h, const unsigned char* __restrict__ h8,
    const int* __restrict__ start, const int2* __restrict__ sedge,
    const float* __restrict__ ew, const float* __restrict__ eb,
    const float* __restrict__ epsp, int layer,
    unsigned short* __restrict__ z, int n) {
    int node = (blockIdx.x * blockDim.x + threadIdx.x) >> 6;
    int lane = threadIdx.x & 63;
    if (node >= n) return;
    int c = lane << 1;
    float2 wv = *(const float2*)(ew + c);
    float2 bv = *(const float2*)(eb + c);
    float2 acc = make_float2(0.f, 0.f);
    int s0 = start[node], s1 = start[node + 1];
    for (int j = s0; j < s1; j += 8) {
        int2 e[8];
        unsigned short v8[8];
        #pragma unroll
        for (int k = 0; k < 8; ++k) {
            int idx = j + k;
            e[k] = sedge[idx < s1 ? idx : (s1 - 1)];
        }
        #pragma unroll
        for (int k = 0; k < 8; ++k)
            v8[k] = *(const unsigned short*)(h8 + (size_t)e[k].x * H + c);
        #pragma unroll
        for (int k = 0; k < 8; ++k) {
            float valid = (j + k < s1) ? 1.f : 0.f;
            float a = __uint_as_float((unsigned)e[k].y & 0xffff0000u);
            floatx2 hv = __builtin_amdgcn_cvt_pk_f32_fp8((int)v8[k], false);
            acc.x += valid * fmaxf(fmaf(a, wv.x, bv.x) + hv.x, 0.f);
            acc.y += valid * fmaxf(fmaf(a, wv.y, bv.y) + hv.y, 0.f);
        }
    }
    float ev = 1.0f + epsp[layer];
    ushort2 hv = *(const ushort2*)(h + (size_t)node * H + c);
    ushort2 p;
    p.x = f2bf(fmaf(ev, bf2f(hv.x), acc.x));
    p.y = f2bf(fmaf(ev, bf2f(hv.y), acc.y));
    *(ushort2*)(z + (size_t)node * H + c) = p;
}

// ---- MFMA node MLP: h = bf16(relu(BN(relu(z@w1+b1)@w2+b2))), bf16 in/out ----
__global__ __launch_bounds__(256) void mfma_mlp_kernel(
    unsigned short* __restrict__ h, const unsigned short* __restrict__ z,
    const unsigned short* __restrict__ w1t, const float* __restrict__ b1,
    const unsigned short* __restrict__ w2t, const float* __restrict__ b2,
    const float* __restrict__ gamma, const float* __restrict__ beta,
    const float* __restrict__ mean, const float* __restrict__ var, int n) {
    __shared__ unsigned short ts[TMM * TP];
    const int tid = threadIdx.x;
    const int wid = tid >> 6;
    const int lane = tid & 63;
    const int m = lane & 15;     // A row within 16 / B col
    const int q = lane >> 4;     // quad
    const int row0 = blockIdx.x * TMM + wid * 16;

    // ---------- GEMM1: t = relu(z @ w1 + b1) ----------
    floatx4 acc[8];
    #pragma unroll
    for (int ct = 0; ct < 8; ++ct) acc[ct] = (floatx4)(0.f);

    const unsigned short* zrow = z + (size_t)(row0 + m) * H + q * 8;
    #pragma unroll
    for (int kb = 0; kb < H; kb += 32) {
        short8 a = *(const short8*)(zrow + kb);
        #pragma unroll
        for (int ct = 0; ct < 8; ++ct) {
            short8 b = *(const short8*)(w1t + (size_t)(ct * 16 + m) * H + kb + q * 8);
            acc[ct] = __builtin_amdgcn_mfma_f32_16x16x32_bf16(a, b, acc[ct], 0, 0, 0);
        }
    }
    unsigned short* tw = ts + wid * 16 * TP;
    #pragma unroll
    for (int ct = 0; ct < 8; ++ct) {
        float bb = b1[ct * 16 + m];
        #pragma unroll
        for (int r = 0; r < 4; ++r) {
            float v = fmaxf(acc[ct][r] + bb, 0.f);
            tw[(q * 4 + r) * TP + ct * 16 + m] = f2bf(v);
        }
    }

    // ---------- GEMM2: z2 = t @ w2 + b2, then BN + relu ----------
    floatx4 acc2[8];
    #pragma unroll
    for (int ct = 0; ct < 8; ++ct) acc2[ct] = (floatx4)(0.f);

    const unsigned short* trow = tw + m * TP + q * 8;
    #pragma unroll
    for (int kb = 0; kb < H; kb += 32) {
        short8 a = *(const short8*)(trow + kb);
        #pragma unroll
        for (int ct = 0; ct < 8; ++ct) {
            short8 b = *(const short8*)(w2t + (size_t)(ct * 16 + m) * H + kb + q * 8);
            acc2[ct] = __builtin_amdgcn_mfma_f32_16x16x32_bf16(a, b, acc2[ct], 0, 0, 0);
        }
    }
    #pragma unroll
    for (int ct = 0; ct < 8; ++ct) {
        int col = ct * 16 + m;
        float bb = b2[col];
        float sc = gamma[col] * rsqrtf(var[col] + 1e-5f);
        float mn = mean[col];
        float bt = beta[col];
        #pragma unroll
        for (int r = 0; r < 4; ++r) {
            int grow = row0 + q * 4 + r;
            if (grow < n) {
                float v = fmaxf((acc2[ct][r] + bb - mn) * sc + bt, 0.f);
                h[(size_t)grow * H + col] = f2bf(v);
            }
        }
    }
}

// ---- graph boundaries from sorted batch: gstart[g] = first node of graph g ----
__global__ void gbound_kernel(const int* __restrict__ batch, int* __restrict__ gstart, int n) {
    int i = blockIdx.x * blockDim.x + threadIdx.x;
    if (i >= n) return;
    int b = batch[i];
    if (i == 0) {
        for (int g = 0; g <= b; ++g) gstart[g] = 0;
    } else {
        int p = batch[i - 1];
        for (int g = p + 1; g <= b; ++g) gstart[g] = i;
    }
    if (i == n - 1) {
        for (int g = b + 1; g <= NGRAPH; ++g) gstart[g] = n;
    }
}

// ---- global mean pool: segmented gather of bf16 h, LDS reduce, few atomics ----
__global__ __launch_bounds__(256) void pool_kernel(const unsigned short* __restrict__ h,
                                                   const int* __restrict__ gstart,
                                                   float* __restrict__ sums) {
    __shared__ float4 buf[8][32];
    const int g = blockIdx.x;       // graph
    const int split = blockIdx.y;   // 0..7
    const int t = threadIdx.x;
    const int c32 = t & 31;
    const int c = c32 << 2;
    const int r = t >> 5;           // 0..7
    int s0 = gstart[g], s1 = gstart[g + 1];
    int len = s1 - s0;
    int chunk = (len + 7) >> 3;
    int a = s0 + split * chunk;
    int b = min(a + chunk, s1);
    float4 acc = make_float4(0.f, 0.f, 0.f, 0.f);
    for (int i = a + r; i < b; i += 8) {
        ushort4 v = *(const ushort4*)(h + (size_t)i * H + c);
        acc.x += bf2f(v.x); acc.y += bf2f(v.y); acc.z += bf2f(v.z); acc.w += bf2f(v.w);
    }
    buf[r][c32] = acc;
    __syncthreads();
    if (r == 0) {
        float4 s = buf[0][c32];
        #pragma unroll
        for (int k = 1; k < 8; ++k) {
            float4 v = buf[k][c32];
            s.x += v.x; s.y += v.y; s.z += v.z; s.w += v.w;
        }
        float* sp = sums + (size_t)g * H + c;
        atomicAdd(sp + 0, s.x);
        atomicAdd(sp + 1, s.y);
        atomicAdd(sp + 2, s.z);
        atomicAdd(sp + 3, s.w);
    }
}

// ---------------- classifier: sigmoid(relu(g@w1+b1)@w2+b2) ----------------
__global__ void cls_kernel(const float* __restrict__ sums, const int* __restrict__ gstart,
                           const float* __restrict__ w1, const float* __restrict__ b1,
                           const float* __restrict__ w2, const float* __restrict__ b2,
                           float* __restrict__ out) {
    int g = blockIdx.x;     // 64 graphs
    int m = threadIdx.x;    // 64 mids
    float cnt = (float)(gstart[g + 1] - gstart[g]);
    float inv = 1.0f / fmaxf(cnt, 1.0f);
    float acc = 0.f;
    for (int k = 0; k < H; ++k) {
        float gk = sums[(size_t)g * H + k] * inv;
        acc += gk * w1[(size_t)k * 64 + m];
    }
    float tm = fmaxf(acc + b1[m], 0.f);
    float p = tm * w2[m];
    #pragma unroll
    for (int off = 32; off > 0; off >>= 1) p += __shfl_down(p, off, 64);
    if (m == 0) out[g] = 1.f / (1.f + expf(-(p + b2[0])));
}

extern "C" void kernel_launch(void* const* d_in, const int* in_sizes, int n_in,
                              void* d_out, int out_size, void* d_ws, size_t ws_size,
                              hipStream_t stream) {
    const float* x      = (const float*)d_in[0];
    const int*   ei     = (const int*)d_in[1];
    const float* ea     = (const float*)d_in[2];
    const int*   batch  = (const int*)d_in[3];
    const float* enc_w  = (const float*)d_in[4];
    const float* enc_b  = (const float*)d_in[5];
    const float* edge_w = (const float*)d_in[6];
    const float* edge_b = (const float*)d_in[7];
    const float* eps    = (const float*)d_in[8];
    const float* mlp_w1 = (const float*)d_in[9];
    const float* mlp_b1 = (const float*)d_in[10];
    const float* mlp_w2 = (const float*)d_in[11];
    const float* mlp_b2 = (const float*)d_in[12];
    const float* bn_g   = (const float*)d_in[13];
    const float* bn_b   = (const float*)d_in[14];
    const float* bn_m   = (const float*)d_in[15];
    const float* bn_v   = (const float*)d_in[16];
    const float* cls_w1 = (const float*)d_in[17];
    const float* cls_b1 = (const float*)d_in[18];
    const float* cls_w2 = (const float*)d_in[19];
    const float* cls_b2 = (const float*)d_in[20];
    float* out = (float*)d_out;

    const int n = in_sizes[0];        // 100000
    const int ne = in_sizes[2];       // 1600000
    const int nb = (n + 1023) / 1024; // scan blocks
    const int nbuck = (n + (1 << BSH) - 1) >> BSH;  // 256-node buckets

    // workspace layout (regions kept 16B-aligned)
    unsigned short* hb  = (unsigned short*)d_ws;                    // N*H bf16
    unsigned short* zb  = hb + (size_t)n * H;                       // N*H bf16
    unsigned char* h8   = (unsigned char*)(zb + (size_t)n * H);     // N*H fp8
    float* sums         = (float*)(h8 + (size_t)n * H);             // G*H
    int*   gstart       = (int*)(sums + (size_t)NGRAPH * H);        // G+4
    int*   deg          = gstart + NGRAPH + 4;                      // N
    int*   start        = deg + n;                                  // N+4
    int*   bcursor      = start + n + 4;                            // MAXB
    int*   bsum         = bcursor + MAXB;                           // 256
    int*   bscan        = bsum + 256;                               // 256
    unsigned short* w1t = (unsigned short*)(bscan + 256);           // 2*128*128
    unsigned short* w2t = w1t + 2 * 16384;                          // 2*128*128
    int2*  sedge2       = (int2*)(w2t + 2 * 16384);                 // E (binned)
    int2*  sedge        = sedge2 + ne;                              // E (sorted)

    hipMemsetAsync(sums, 0, (size_t)NGRAPH * H * sizeof(float), stream);
    hipMemsetAsync(deg, 0, (size_t)n * sizeof(int), stream);
    hipMemsetAsync(bcursor, 0, (size_t)MAXB * sizeof(int), stream);

    // weight prep (bf16 transpose) — once per call
    prep_kernel<<<128, 256, 0, stream>>>(mlp_w1, mlp_w2, w1t, w2t);

    // ---- counting sort of edges by dst (once; reused both layers) ----
    hist_kernel<<<(ne + 255) / 256, 256, 0, stream>>>(ei, deg, ne);
    scan1_kernel<<<nb, 256, 0, stream>>>(deg, start, bsum, n);
    scan2_kernel<<<1, 256, 0, stream>>>(bsum, bscan, start, nb, n);
    scan3_kernel<<<(n + 255) / 256, 256, 0, stream>>>(start, bscan, n);
    binA_kernel<<<(ne + 4095) / 4096, 256, 0, stream>>>(ei, ea, start, bcursor, sedge2, ne, n, nbuck);
    binB_kernel<<<nbuck, 256, 0, stream>>>(sedge2, start, sedge, n);

    // graph boundaries for pooling
    gbound_kernel<<<(n + 255) / 256, 256, 0, stream>>>(batch, gstart, n);

    // encoder (writes bf16 h and fp8 shadow)
    {
        int threads = n * 32;
        enc_kernel<<<(threads + 255) / 256, 256, 0, stream>>>(x, enc_w, enc_b, hb, h8, n);
    }

    for (int l = 0; l < NLAYERS; ++l) {
        {
            int threads = n * 64;
            aggregate_kernel<<<(threads + 255) / 256, 256, 0, stream>>>(
                hb, h8, start, sedge, edge_w, edge_b, eps, l, zb, n);
        }
        mfma_mlp_kernel<<<(n + TMM - 1) / TMM, 256, 0, stream>>>(
            hb, zb,
            w1t + (size_t)l * 16384, mlp_b1 + (size_t)l * H,
            w2t + (size_t)l * 16384, mlp_b2 + (size_t)l * H,
            bn_g + (size_t)l * H, bn_b + (size_t)l * H,
            bn_m + (size_t)l * H, bn_v + (size_t)l * H, n);
        if (l == 0) {
            int threads = n * 32;
            cast_kernel<<<(threads + 255) / 256, 256, 0, stream>>>(hb, h8, n);
        }
    }

    pool_kernel<<<dim3(NGRAPH, 8), 256, 0, stream>>>(hb, gstart, sums);
    cls_kernel<<<NGRAPH, 64, 0, stream>>>(sums, gstart, cls_w1, cls_b1, cls_w2, cls_b2, out);
}

// Round 9
// 529.001 us; speedup vs baseline: 1.1828x; 1.0606x over previous
//
#include <hip/hip_runtime.h>
#include <hip/hip_bf16.h>

#define H 128
#define NGRAPH 64
#define NLAYERS 2
#define TMM 64          // rows per MLP block
#define TP 136          // t-tile LDS row stride in bf16 (pad 8)
#define BSH 8           // bucket shift: 256 nodes per bucket
#define MAXB 512        // max buckets (n <= 131072)

typedef short short8 __attribute__((ext_vector_type(8)));
typedef float floatx4 __attribute__((ext_vector_type(4)));
typedef float floatx2 __attribute__((ext_vector_type(2)));

static __device__ __forceinline__ unsigned short f2bf(float v) {
    __hip_bfloat16 b = __float2bfloat16(v);
    return *(unsigned short*)&b;
}
static __device__ __forceinline__ float bf2f(unsigned short u) {
    return __uint_as_float(((unsigned int)u) << 16);
}
// pack 4 f32 -> 4 fp8(e4m3) bytes
static __device__ __forceinline__ int pack4_fp8(float a, float b, float c, float d) {
    int p = __builtin_amdgcn_cvt_pk_fp8_f32(a, b, 0, false);
    p = __builtin_amdgcn_cvt_pk_fp8_f32(c, d, p, true);
    return p;
}

// ------- encoder: h = bf16(x*w+b), plus fp8 shadow h8 for gathers -------
__global__ void enc_kernel(const float* __restrict__ x, const float* __restrict__ w,
                           const float* __restrict__ b, unsigned short* __restrict__ h,
                           unsigned char* __restrict__ h8, int n) {
    int t = blockIdx.x * blockDim.x + threadIdx.x;
    int i = t >> 5;            // node
    int c = (t & 31) << 2;     // feature*4
    if (i >= n) return;
    float xv = x[i];
    float4 wv = *(const float4*)(w + c);
    float4 bv = *(const float4*)(b + c);
    float4 o;
    o.x = xv * wv.x + bv.x;
    o.y = xv * wv.y + bv.y;
    o.z = xv * wv.z + bv.z;
    o.w = xv * wv.w + bv.w;
    ushort4 ob;
    ob.x = f2bf(o.x); ob.y = f2bf(o.y); ob.z = f2bf(o.z); ob.w = f2bf(o.w);
    *(ushort4*)(h + (size_t)i * H + c) = ob;
    *(int*)(h8 + (size_t)i * H + c) = pack4_fp8(o.x, o.y, o.z, o.w);
}

// ------- cast bf16 h -> fp8 shadow (after layer-0 MLP) -------
__global__ void cast_kernel(const unsigned short* __restrict__ h,
                            unsigned char* __restrict__ h8, int n) {
    int t = blockIdx.x * blockDim.x + threadIdx.x;
    int i = t >> 5;
    int c = (t & 31) << 2;
    if (i >= n) return;
    ushort4 v = *(const ushort4*)(h + (size_t)i * H + c);
    *(int*)(h8 + (size_t)i * H + c) =
        pack4_fp8(bf2f(v.x), bf2f(v.y), bf2f(v.z), bf2f(v.w));
}

// ------- prep: cast+transpose mlp weights to bf16 [l][n][k] -------
__global__ void prep_kernel(const float* __restrict__ w1, const float* __restrict__ w2,
                            unsigned short* __restrict__ w1t, unsigned short* __restrict__ w2t) {
    int idx = blockIdx.x * blockDim.x + threadIdx.x;   // 2*128*128
    int l = idx >> 14;
    int r = idx & 16383;
    int nn = r >> 7;
    int kk = r & 127;
    w1t[(size_t)l * 16384 + nn * 128 + kk] = f2bf(w1[(size_t)l * 16384 + kk * 128 + nn]);
    w2t[(size_t)l * 16384 + nn * 128 + kk] = f2bf(w2[(size_t)l * 16384 + kk * 128 + nn]);
}

// ---------------- counting-sort by dst: histogram ----------------
__global__ void hist_kernel(const int* __restrict__ ei, int* __restrict__ deg, int ne) {
    int e = blockIdx.x * blockDim.x + threadIdx.x;
    if (e >= ne) return;
    atomicAdd(&deg[ei[ne + e]], 1);
}

// -------- hierarchical exclusive scan, level 1: 1024 elems per block --------
__global__ __launch_bounds__(256) void scan1_kernel(const int* __restrict__ deg,
                                                    int* __restrict__ start,
                                                    int* __restrict__ bsum, int n) {
    __shared__ int wsum[4];
    const int t = threadIdx.x;
    const int lane = t & 63;
    const int wid = t >> 6;
    const int base = blockIdx.x * 1024 + t * 4;
    int4 v = make_int4(0, 0, 0, 0);
    if (base + 3 < n) v = *(const int4*)(deg + base);
    else {
        if (base + 0 < n) v.x = deg[base + 0];
        if (base + 1 < n) v.y = deg[base + 1];
        if (base + 2 < n) v.z = deg[base + 2];
    }
    int s = v.x + v.y + v.z + v.w;
    int incl = s;
    #pragma unroll
    for (int off = 1; off < 64; off <<= 1) {
        int u = __shfl_up(incl, off, 64);
        if (lane >= off) incl += u;
    }
    if (lane == 63) wsum[wid] = incl;
    __syncthreads();
    int woff = 0;
    #pragma unroll
    for (int k = 0; k < 4; ++k) if (k < wid) woff += wsum[k];
    int excl = woff + incl - s;
    int4 o;
    o.x = excl;
    o.y = o.x + v.x;
    o.z = o.y + v.y;
    o.w = o.z + v.z;
    if (base + 3 < n) *(int4*)(start + base) = o;
    else {
        if (base + 0 < n) start[base + 0] = o.x;
        if (base + 1 < n) start[base + 1] = o.y;
        if (base + 2 < n) start[base + 2] = o.z;
    }
    if (t == 255) bsum[blockIdx.x] = woff + incl;
}

// -------- scan level 2: scan block sums (nb <= 256), write total to start[n] --
__global__ __launch_bounds__(256) void scan2_kernel(const int* __restrict__ bsum,
                                                    int* __restrict__ bscan,
                                                    int* __restrict__ start, int nb, int n) {
    __shared__ int wsum[4];
    const int t = threadIdx.x;
    const int lane = t & 63;
    const int wid = t >> 6;
    int v = (t < nb) ? bsum[t] : 0;
    int incl = v;
    #pragma unroll
    for (int off = 1; off < 64; off <<= 1) {
        int u = __shfl_up(incl, off, 64);
        if (lane >= off) incl += u;
    }
    if (lane == 63) wsum[wid] = incl;
    __syncthreads();
    int woff = 0;
    #pragma unroll
    for (int k = 0; k < 4; ++k) if (k < wid) woff += wsum[k];
    if (t < nb) bscan[t] = woff + incl - v;
    if (t == 255) start[n] = woff + incl;
}

// -------- scan level 3: add block offsets --------
__global__ void scan3_kernel(int* __restrict__ start, const int* __restrict__ bscan, int n) {
    int i = blockIdx.x * blockDim.x + threadIdx.x;
    if (i < n) start[i] += bscan[i >> 10];
}

// ---- sort phase A: bin edges into 256-node buckets, block-coalesced runs ----
// entry: x = src, y = (attr_bf16 << 16) | local_dst(8b)
__global__ __launch_bounds__(256) void binA_kernel(
    const int* __restrict__ ei, const float* __restrict__ ea,
    const int* __restrict__ start, int* __restrict__ bcursor,
    int2* __restrict__ sedge2, int ne, int n, int nbuck) {
    __shared__ int hist[MAXB];
    __shared__ int gpos[MAXB];
    const int t = threadIdx.x;
    const int e0 = blockIdx.x * 4096;
    for (int k = t; k < MAXB; k += 256) hist[k] = 0;
    __syncthreads();
    int dsts[16];
    #pragma unroll
    for (int k = 0; k < 16; ++k) {
        int e = e0 + k * 256 + t;
        int d = (e < ne) ? ei[ne + e] : -1;
        dsts[k] = d;
        if (d >= 0) atomicAdd(&hist[d >> BSH], 1);
    }
    __syncthreads();
    for (int b = t; b < nbuck; b += 256) {
        int c = hist[b];
        gpos[b] = (c > 0) ? (start[b << BSH] + atomicAdd(&bcursor[b], c)) : 0;
    }
    __syncthreads();
    for (int k = t; k < MAXB; k += 256) hist[k] = 0;   // reuse as local cursor
    __syncthreads();
    #pragma unroll
    for (int k = 0; k < 16; ++k) {
        int d = dsts[k];
        if (d >= 0) {
            int e = e0 + k * 256 + t;
            int b = d >> BSH;
            int idx = atomicAdd(&hist[b], 1);
            int2 p;
            p.x = ei[e];
            p.y = ((int)f2bf(ea[e]) << 16) | (d & ((1 << BSH) - 1));
            sedge2[gpos[b] + idx] = p;
        }
    }
}

// ---- sort phase B: exact scatter within bucket (one block per bucket) ----
// strips local_dst from y so aggregate can use it as a float directly
__global__ __launch_bounds__(256) void binB_kernel(
    const int2* __restrict__ sedge2, const int* __restrict__ start,
    int2* __restrict__ sedge, int n) {
    __shared__ int lcur[1 << BSH];
    const int node0 = blockIdx.x << BSH;
    const int t = threadIdx.x;
    lcur[t] = 0;
    __syncthreads();
    int s0 = start[node0];
    int s1 = start[min(node0 + (1 << BSH), n)];
    for (int i = s0 + t; i < s1; i += 256) {
        int2 p = sedge2[i];
        int ld = p.y & ((1 << BSH) - 1);
        int idx = atomicAdd(&lcur[ld], 1);
        p.y = (int)((unsigned)p.y & 0xffff0000u);   // attr bf16 only
        sedge[start[node0 + ld] + idx] = p;
    }
}

// ---- segment-reduce gather: z[i] = (1+eps)*h[i] + sum_j relu(h8[src_j]+e_j) ----
// one wave per node; fp8 h rows (128 B gather). Full 8-wide chunks carry ZERO
// predication; single masked 8-wide tail chunk handles the remainder.
__global__ __launch_bounds__(256) void aggregate_kernel(
    const unsigned short* __restrict__ h, const unsigned char* __restrict__ h8,
    const int* __restrict__ start, const int2* __restrict__ sedge,
    const float* __restrict__ ew, const float* __restrict__ eb,
    const float* __restrict__ epsp, int layer,
    unsigned short* __restrict__ z, int n) {
    int node = (blockIdx.x * blockDim.x + threadIdx.x) >> 6;
    int lane = threadIdx.x & 63;
    if (node >= n) return;
    int c = lane << 1;
    float2 wv = *(const float2*)(ew + c);
    float2 bv = *(const float2*)(eb + c);
    float2 acc = make_float2(0.f, 0.f);
    int s0 = start[node], s1 = start[node + 1];
    int j = s0;
    // full chunks: no clamp, no mask
    for (; j + 8 <= s1; j += 8) {
        int2 e[8];
        unsigned short v8[8];
        #pragma unroll
        for (int k = 0; k < 8; ++k) e[k] = sedge[j + k];
        #pragma unroll
        for (int k = 0; k < 8; ++k)
            v8[k] = *(const unsigned short*)(h8 + (size_t)e[k].x * H + c);
        #pragma unroll
        for (int k = 0; k < 8; ++k) {
            float a = __int_as_float(e[k].y);
            floatx2 hv = __builtin_amdgcn_cvt_pk_f32_fp8((int)v8[k], false);
            acc.x += fmaxf(fmaf(a, wv.x, bv.x) + hv.x, 0.f);
            acc.y += fmaxf(fmaf(a, wv.y, bv.y) + hv.y, 0.f);
        }
    }
    // single masked tail chunk
    if (j < s1) {
        int2 e[8];
        unsigned short v8[8];
        #pragma unroll
        for (int k = 0; k < 8; ++k) {
            int idx = j + k;
            e[k] = sedge[idx < s1 ? idx : (s1 - 1)];
        }
        #pragma unroll
        for (int k = 0; k < 8; ++k)
            v8[k] = *(const unsigned short*)(h8 + (size_t)e[k].x * H + c);
        #pragma unroll
        for (int k = 0; k < 8; ++k) {
            float valid = (j + k < s1) ? 1.f : 0.f;
            float a = __int_as_float(e[k].y);
            floatx2 hv = __builtin_amdgcn_cvt_pk_f32_fp8((int)v8[k], false);
            acc.x += valid * fmaxf(fmaf(a, wv.x, bv.x) + hv.x, 0.f);
            acc.y += valid * fmaxf(fmaf(a, wv.y, bv.y) + hv.y, 0.f);
        }
    }
    float ev = 1.0f + epsp[layer];
    ushort2 hv = *(const ushort2*)(h + (size_t)node * H + c);
    ushort2 p;
    p.x = f2bf(fmaf(ev, bf2f(hv.x), acc.x));
    p.y = f2bf(fmaf(ev, bf2f(hv.y), acc.y));
    *(ushort2*)(z + (size_t)node * H + c) = p;
}

// ---- MFMA node MLP: h = bf16(relu(BN(relu(z@w1+b1)@w2+b2))), bf16 in/out ----
__global__ __launch_bounds__(256) void mfma_mlp_kernel(
    unsigned short* __restrict__ h, const unsigned short* __restrict__ z,
    const unsigned short* __restrict__ w1t, const float* __restrict__ b1,
    const unsigned short* __restrict__ w2t, const float* __restrict__ b2,
    const float* __restrict__ gamma, const float* __restrict__ beta,
    const float* __restrict__ mean, const float* __restrict__ var, int n) {
    __shared__ unsigned short ts[TMM * TP];
    const int tid = threadIdx.x;
    const int wid = tid >> 6;
    const int lane = tid & 63;
    const int m = lane & 15;     // A row within 16 / B col
    const int q = lane >> 4;     // quad
    const int row0 = blockIdx.x * TMM + wid * 16;

    // ---------- GEMM1: t = relu(z @ w1 + b1) ----------
    floatx4 acc[8];
    #pragma unroll
    for (int ct = 0; ct < 8; ++ct) acc[ct] = (floatx4)(0.f);

    const unsigned short* zrow = z + (size_t)(row0 + m) * H + q * 8;
    #pragma unroll
    for (int kb = 0; kb < H; kb += 32) {
        short8 a = *(const short8*)(zrow + kb);
        #pragma unroll
        for (int ct = 0; ct < 8; ++ct) {
            short8 b = *(const short8*)(w1t + (size_t)(ct * 16 + m) * H + kb + q * 8);
            acc[ct] = __builtin_amdgcn_mfma_f32_16x16x32_bf16(a, b, acc[ct], 0, 0, 0);
        }
    }
    unsigned short* tw = ts + wid * 16 * TP;
    #pragma unroll
    for (int ct = 0; ct < 8; ++ct) {
        float bb = b1[ct * 16 + m];
        #pragma unroll
        for (int r = 0; r < 4; ++r) {
            float v = fmaxf(acc[ct][r] + bb, 0.f);
            tw[(q * 4 + r) * TP + ct * 16 + m] = f2bf(v);
        }
    }

    // ---------- GEMM2: z2 = t @ w2 + b2, then BN + relu ----------
    floatx4 acc2[8];
    #pragma unroll
    for (int ct = 0; ct < 8; ++ct) acc2[ct] = (floatx4)(0.f);

    const unsigned short* trow = tw + m * TP + q * 8;
    #pragma unroll
    for (int kb = 0; kb < H; kb += 32) {
        short8 a = *(const short8*)(trow + kb);
        #pragma unroll
        for (int ct = 0; ct < 8; ++ct) {
            short8 b = *(const short8*)(w2t + (size_t)(ct * 16 + m) * H + kb + q * 8);
            acc2[ct] = __builtin_amdgcn_mfma_f32_16x16x32_bf16(a, b, acc2[ct], 0, 0, 0);
        }
    }
    #pragma unroll
    for (int ct = 0; ct < 8; ++ct) {
        int col = ct * 16 + m;
        float bb = b2[col];
        float sc = gamma[col] * rsqrtf(var[col] + 1e-5f);
        float mn = mean[col];
        float bt = beta[col];
        #pragma unroll
        for (int r = 0; r < 4; ++r) {
            int grow = row0 + q * 4 + r;
            if (grow < n) {
                float v = fmaxf((acc2[ct][r] + bb - mn) * sc + bt, 0.f);
                h[(size_t)grow * H + col] = f2bf(v);
            }
        }
    }
}

// ---- graph boundaries from sorted batch: gstart[g] = first node of graph g ----
__global__ void gbound_kernel(const int* __restrict__ batch, int* __restrict__ gstart, int n) {
    int i = blockIdx.x * blockDim.x + threadIdx.x;
    if (i >= n) return;
    int b = batch[i];
    if (i == 0) {
        for (int g = 0; g <= b; ++g) gstart[g] = 0;
    } else {
        int p = batch[i - 1];
        for (int g = p + 1; g <= b; ++g) gstart[g] = i;
    }
    if (i == n - 1) {
        for (int g = b + 1; g <= NGRAPH; ++g) gstart[g] = n;
    }
}

// ---- global mean pool: segmented gather of bf16 h, LDS reduce, few atomics ----
__global__ __launch_bounds__(256) void pool_kernel(const unsigned short* __restrict__ h,
                                                   const int* __restrict__ gstart,
                                                   float* __restrict__ sums) {
    __shared__ float4 buf[8][32];
    const int g = blockIdx.x;       // graph
    const int split = blockIdx.y;   // 0..7
    const int t = threadIdx.x;
    const int c32 = t & 31;
    const int c = c32 << 2;
    const int r = t >> 5;           // 0..7
    int s0 = gstart[g], s1 = gstart[g + 1];
    int len = s1 - s0;
    int chunk = (len + 7) >> 3;
    int a = s0 + split * chunk;
    int b = min(a + chunk, s1);
    float4 acc = make_float4(0.f, 0.f, 0.f, 0.f);
    for (int i = a + r; i < b; i += 8) {
        ushort4 v = *(const ushort4*)(h + (size_t)i * H + c);
        acc.x += bf2f(v.x); acc.y += bf2f(v.y); acc.z += bf2f(v.z); acc.w += bf2f(v.w);
    }
    buf[r][c32] = acc;
    __syncthreads();
    if (r == 0) {
        float4 s = buf[0][c32];
        #pragma unroll
        for (int k = 1; k < 8; ++k) {
            float4 v = buf[k][c32];
            s.x += v.x; s.y += v.y; s.z += v.z; s.w += v.w;
        }
        float* sp = sums + (size_t)g * H + c;
        atomicAdd(sp + 0, s.x);
        atomicAdd(sp + 1, s.y);
        atomicAdd(sp + 2, s.z);
        atomicAdd(sp + 3, s.w);
    }
}

// ---------------- classifier: sigmoid(relu(g@w1+b1)@w2+b2) ----------------
__global__ void cls_kernel(const float* __restrict__ sums, const int* __restrict__ gstart,
                           const float* __restrict__ w1, const float* __restrict__ b1,
                           const float* __restrict__ w2, const float* __restrict__ b2,
                           float* __restrict__ out) {
    int g = blockIdx.x;     // 64 graphs
    int m = threadIdx.x;    // 64 mids
    float cnt = (float)(gstart[g + 1] - gstart[g]);
    float inv = 1.0f / fmaxf(cnt, 1.0f);
    float acc = 0.f;
    for (int k = 0; k < H; ++k) {
        float gk = sums[(size_t)g * H + k] * inv;
        acc += gk * w1[(size_t)k * 64 + m];
    }
    float tm = fmaxf(acc + b1[m], 0.f);
    float p = tm * w2[m];
    #pragma unroll
    for (int off = 32; off > 0; off >>= 1) p += __shfl_down(p, off, 64);
    if (m == 0) out[g] = 1.f / (1.f + expf(-(p + b2[0])));
}

extern "C" void kernel_launch(void* const* d_in, const int* in_sizes, int n_in,
                              void* d_out, int out_size, void* d_ws, size_t ws_size,
                              hipStream_t stream) {
    const float* x      = (const float*)d_in[0];
    const int*   ei     = (const int*)d_in[1];
    const float* ea     = (const float*)d_in[2];
    const int*   batch  = (const int*)d_in[3];
    const float* enc_w  = (const float*)d_in[4];
    const float* enc_b  = (const float*)d_in[5];
    const float* edge_w = (const float*)d_in[6];
    const float* edge_b = (const float*)d_in[7];
    const float* eps    = (const float*)d_in[8];
    const float* mlp_w1 = (const float*)d_in[9];
    const float* mlp_b1 = (const float*)d_in[10];
    const float* mlp_w2 = (const float*)d_in[11];
    const float* mlp_b2 = (const float*)d_in[12];
    const float* bn_g   = (const float*)d_in[13];
    const float* bn_b   = (const float*)d_in[14];
    const float* bn_m   = (const float*)d_in[15];
    const float* bn_v   = (const float*)d_in[16];
    const float* cls_w1 = (const float*)d_in[17];
    const float* cls_b1 = (const float*)d_in[18];
    const float* cls_w2 = (const float*)d_in[19];
    const float* cls_b2 = (const float*)d_in[20];
    float* out = (float*)d_out;

    const int n = in_sizes[0];        // 100000
    const int ne = in_sizes[2];       // 1600000
    const int nb = (n + 1023) / 1024; // scan blocks
    const int nbuck = (n + (1 << BSH) - 1) >> BSH;  // 256-node buckets

    // workspace layout (regions kept 16B-aligned)
    unsigned short* hb  = (unsigned short*)d_ws;                    // N*H bf16
    unsigned short* zb  = hb + (size_t)n * H;                       // N*H bf16
    unsigned char* h8   = (unsigned char*)(zb + (size_t)n * H);     // N*H fp8
    float* sums         = (float*)(h8 + (size_t)n * H);             // G*H
    int*   gstart       = (int*)(sums + (size_t)NGRAPH * H);        // G+4
    int*   deg          = gstart + NGRAPH + 4;                      // N
    int*   start        = deg + n;                                  // N+4
    int*   bcursor      = start + n + 4;                            // MAXB
    int*   bsum         = bcursor + MAXB;                           // 256
    int*   bscan        = bsum + 256;                               // 256
    unsigned short* w1t = (unsigned short*)(bscan + 256);           // 2*128*128
    unsigned short* w2t = w1t + 2 * 16384;                          // 2*128*128
    int2*  sedge2       = (int2*)(w2t + 2 * 16384);                 // E (binned)
    int2*  sedge        = sedge2 + ne;                              // E (sorted)

    hipMemsetAsync(sums, 0, (size_t)NGRAPH * H * sizeof(float), stream);
    hipMemsetAsync(deg, 0, (size_t)n * sizeof(int), stream);
    hipMemsetAsync(bcursor, 0, (size_t)MAXB * sizeof(int), stream);

    // weight prep (bf16 transpose) — once per call
    prep_kernel<<<128, 256, 0, stream>>>(mlp_w1, mlp_w2, w1t, w2t);

    // ---- counting sort of edges by dst (once; reused both layers) ----
    hist_kernel<<<(ne + 255) / 256, 256, 0, stream>>>(ei, deg, ne);
    scan1_kernel<<<nb, 256, 0, stream>>>(deg, start, bsum, n);
    scan2_kernel<<<1, 256, 0, stream>>>(bsum, bscan, start, nb, n);
    scan3_kernel<<<(n + 255) / 256, 256, 0, stream>>>(start, bscan, n);
    binA_kernel<<<(ne + 4095) / 4096, 256, 0, stream>>>(ei, ea, start, bcursor, sedge2, ne, n, nbuck);
    binB_kernel<<<nbuck, 256, 0, stream>>>(sedge2, start, sedge, n);

    // graph boundaries for pooling
    gbound_kernel<<<(n + 255) / 256, 256, 0, stream>>>(batch, gstart, n);

    // encoder (writes bf16 h and fp8 shadow)
    {
        int threads = n * 32;
        enc_kernel<<<(threads + 255) / 256, 256, 0, stream>>>(x, enc_w, enc_b, hb, h8, n);
    }

    for (int l = 0; l < NLAYERS; ++l) {
        {
            int threads = n * 64;
            aggregate_kernel<<<(threads + 255) / 256, 256, 0, stream>>>(
                hb, h8, start, sedge, edge_w, edge_b, eps, l, zb, n);
        }
        mfma_mlp_kernel<<<(n + TMM - 1) / TMM, 256, 0, stream>>>(
            hb, zb,
            w1t + (size_t)l * 16384, mlp_b1 + (size_t)l * H,
            w2t + (size_t)l * 16384, mlp_b2 + (size_t)l * H,
            bn_g + (size_t)l * H, bn_b + (size_t)l * H,
            bn_m + (size_t)l * H, bn_v + (size_t)l * H, n);
        if (l == 0) {
            int threads = n * 32;
            cast_kernel<<<(threads + 255) / 256, 256, 0, stream>>>(hb, h8, n);
        }
    }

    pool_kernel<<<dim3(NGRAPH, 8), 256, 0, stream>>>(hb, gstart, sums);
    cls_kernel<<<NGRAPH, 64, 0, stream>>>(sums, gstart, cls_w1, cls_b1, cls_w2, cls_b2, out);
}